// Round 6
// baseline (500.022 us; speedup 1.0000x reference)
//
#include <hip/hip_runtime.h>
#include <hip/hip_bf16.h>
#include <math.h>

// ---------------------------------------------------------------------------
// GCN 3-layer forward. R6: reg-fragment MFMA GEMM re-tiled for occupancy —
// 16 rows/wave, 64 rows/block -> 782 blocks (~12 waves/CU), K-loop unrolled
// for load MLP. Packed int2 CSR + 8-way MLP gathers kept from R5.
// ---------------------------------------------------------------------------

using short8  = __attribute__((ext_vector_type(8))) short;
using floatx4 = __attribute__((ext_vector_type(4))) float;

__device__ inline float bf2f(unsigned int u16) {
    union { unsigned int i; float f; } x; x.i = u16 << 16; return x.f;
}
__device__ inline unsigned short f2bf(float f) {
    union { float f; unsigned int i; } x; x.f = f;
    unsigned int lsb = (x.i >> 16) & 1u;
    return (unsigned short)((x.i + 0x7fffu + lsb) >> 16);
}

// ---------------- CSR build ----------------
__global__ void k_zero_i32(int* p, int n) {
    int i = blockIdx.x * 256 + threadIdx.x;
    if (i < n) p[i] = 0;
}

__global__ void k_deg_count(const int* __restrict__ dst, int* deg, int e) {
    int i = blockIdx.x * 256 + threadIdx.x;
    if (i < e) atomicAdd(&deg[dst[i]], 1);
}

__global__ void k_dis(const int* __restrict__ deg, float* dis, int n) {
    int i = blockIdx.x * 256 + threadIdx.x;
    if (i < n) dis[i] = rsqrtf((float)(deg[i] + 1));   // +1 self loop
}

__global__ void k_scan_block(const int* __restrict__ deg, int* incl, int* bsum, int n) {
    __shared__ int s[256];
    int tid = threadIdx.x;
    int i = blockIdx.x * 256 + tid;
    int v = (i < n) ? deg[i] : 0;
    s[tid] = v;
    __syncthreads();
    for (int off = 1; off < 256; off <<= 1) {
        int t = (tid >= off) ? s[tid - off] : 0;
        __syncthreads();
        s[tid] += t;
        __syncthreads();
    }
    if (i < n) incl[i] = s[tid];
    if (tid == 255) bsum[blockIdx.x] = s[255];
}

__global__ void k_scan_bsum(int* bsum, int nb) {   // single block, nb <= 256
    __shared__ int s[256];
    int tid = threadIdx.x;
    s[tid] = (tid < nb) ? bsum[tid] : 0;
    __syncthreads();
    for (int off = 1; off < 256; off <<= 1) {
        int t = (tid >= off) ? s[tid - off] : 0;
        __syncthreads();
        s[tid] += t;
        __syncthreads();
    }
    if (tid < nb) bsum[tid] = s[tid];
}

__global__ void k_scan_final(const int* __restrict__ deg, const int* __restrict__ incl,
                             const int* __restrict__ bsum, int* row_start, int* cursor,
                             int n, int e) {
    int i = blockIdx.x * 256 + threadIdx.x;
    if (i == 0) row_start[n] = e;
    if (i >= n) return;
    int base = (blockIdx.x > 0) ? bsum[blockIdx.x - 1] : 0;
    int excl = base + incl[i] - deg[i];
    row_start[i] = excl;
    cursor[i] = excl;
}

// packed (col, val) per edge: one 8B store -> one cache line touched
__global__ void k_csr_fill(const int* __restrict__ src, const int* __restrict__ dst,
                           const float* __restrict__ dis, int* cursor,
                           int2* __restrict__ cv, int e) {
    int i = blockIdx.x * 256 + threadIdx.x;
    if (i >= e) return;
    int s = src[i], d = dst[i];
    int pos = atomicAdd(&cursor[d], 1);
    float w = dis[s] * dis[d];
    cv[pos] = make_int2(s, __float_as_int(w));
}

// ---------------- W transpose + bf16 cast: Wt[f][k] = bf16(W[k][f]) --------
__global__ void k_wt(const float* __restrict__ W, unsigned short* __restrict__ Wt,
                     int K, int F) {
    int i = blockIdx.x * 256 + threadIdx.x;
    if (i >= K * F) return;
    int k = i / F, f = i % F;
    Wt[(size_t)f * K + k] = f2bf(W[i]);
}

// ---------------- LDS-free register-fragment MFMA GEMM --------------------
// C[n x BN](bf16) = A[n x K] @ Wt^T.  Block = 256 thr = 4 waves; each wave
// owns 16 rows x BN cols (one MFMA M-tile). Grid = n/64 blocks -> ~12
// waves/CU. K-loop unrolled so multiple k-steps' loads are in flight.
template <int K, int BN, bool A_BF16, int UNROLL>
__global__ __launch_bounds__(256) void k_gemm_reg(const void* __restrict__ Av,
                                                  const unsigned short* __restrict__ Wt,
                                                  unsigned short* __restrict__ C, int n) {
    constexpr int NT = BN / 16;
    const int tid = threadIdx.x;
    const int wv = tid >> 6;
    const int lane = tid & 63;
    const int m = lane & 15;
    const int quad = lane >> 4;
    const int rowb = blockIdx.x * 64 + wv * 16;
    const int r0 = min(rowb + m, n - 1);        // clamped loads; stores guarded

    floatx4 acc[NT] = {};

#pragma unroll UNROLL
    for (int k0 = 0; k0 < K; k0 += 32) {
        short8 a0;
        if constexpr (A_BF16) {
            const unsigned short* A = (const unsigned short*)Av;
            a0 = *(const short8*)&A[(size_t)r0 * K + k0 + quad * 8];
        } else {
            const float* A = (const float*)Av;
            float4 f0 = *(const float4*)&A[(size_t)r0 * K + k0 + quad * 8];
            float4 f1 = *(const float4*)&A[(size_t)r0 * K + k0 + quad * 8 + 4];
            a0[0] = (short)f2bf(f0.x); a0[1] = (short)f2bf(f0.y);
            a0[2] = (short)f2bf(f0.z); a0[3] = (short)f2bf(f0.w);
            a0[4] = (short)f2bf(f1.x); a0[5] = (short)f2bf(f1.y);
            a0[6] = (short)f2bf(f1.z); a0[7] = (short)f2bf(f1.w);
        }
#pragma unroll
        for (int t = 0; t < NT; ++t) {
            short8 b = *(const short8*)&Wt[(size_t)(t * 16 + m) * K + k0 + quad * 8];
            acc[t] = __builtin_amdgcn_mfma_f32_16x16x32_bf16(a0, b, acc[t], 0, 0, 0);
        }
    }

    // C/D layout: col = lane&15, row = quad*4 + reg
#pragma unroll
    for (int t = 0; t < NT; ++t) {
        int cc = t * 16 + m;
#pragma unroll
        for (int r = 0; r < 4; ++r) {
            int ga = rowb + quad * 4 + r;
            if (ga < n) C[(size_t)ga * BN + cc] = f2bf(acc[t][r]);
        }
    }
}

// ---------------- Gather F=128 (bf16 h/out), fused bias(+relu) -------------
// 8-way MLP: 8 independent h-row loads per round (clamped idx, zeroed weight).
template <bool RELU>
__global__ __launch_bounds__(256) void k_gather128(
        const int* __restrict__ rs, const int2* __restrict__ cv,
        const float* __restrict__ dis,
        const unsigned short* __restrict__ h, const float* __restrict__ bias,
        unsigned short* __restrict__ out, int n) {
    int node = (blockIdx.x * 256 + threadIdx.x) >> 6;
    int lane = threadIdx.x & 63;
    if (node >= n) return;
    int c = lane * 2;
    float di = dis[node];
    unsigned int hv = *(const unsigned int*)&h[(size_t)node * 128 + c];
    float ax0 = bf2f(hv & 0xffffu) * di * di;
    float ay0 = bf2f(hv >> 16) * di * di;
    float ax1 = 0.f, ay1 = 0.f, ax2 = 0.f, ay2 = 0.f, ax3 = 0.f, ay3 = 0.f;
    int beg = rs[node], end = rs[node + 1];
    int last = end - 1;
    for (int j = beg; j < end; j += 8) {
        int2 c0 = cv[j];
        int2 c1 = cv[min(j + 1, last)];
        int2 c2 = cv[min(j + 2, last)];
        int2 c3 = cv[min(j + 3, last)];
        int2 c4 = cv[min(j + 4, last)];
        int2 c5 = cv[min(j + 5, last)];
        int2 c6 = cv[min(j + 6, last)];
        int2 c7 = cv[min(j + 7, last)];
        float w0 = __int_as_float(c0.y);
        float w1 = (j + 1 < end) ? __int_as_float(c1.y) : 0.f;
        float w2 = (j + 2 < end) ? __int_as_float(c2.y) : 0.f;
        float w3 = (j + 3 < end) ? __int_as_float(c3.y) : 0.f;
        float w4 = (j + 4 < end) ? __int_as_float(c4.y) : 0.f;
        float w5 = (j + 5 < end) ? __int_as_float(c5.y) : 0.f;
        float w6 = (j + 6 < end) ? __int_as_float(c6.y) : 0.f;
        float w7 = (j + 7 < end) ? __int_as_float(c7.y) : 0.f;
        unsigned int v0 = *(const unsigned int*)&h[(size_t)c0.x * 128 + c];
        unsigned int v1 = *(const unsigned int*)&h[(size_t)c1.x * 128 + c];
        unsigned int v2 = *(const unsigned int*)&h[(size_t)c2.x * 128 + c];
        unsigned int v3 = *(const unsigned int*)&h[(size_t)c3.x * 128 + c];
        unsigned int v4 = *(const unsigned int*)&h[(size_t)c4.x * 128 + c];
        unsigned int v5 = *(const unsigned int*)&h[(size_t)c5.x * 128 + c];
        unsigned int v6 = *(const unsigned int*)&h[(size_t)c6.x * 128 + c];
        unsigned int v7 = *(const unsigned int*)&h[(size_t)c7.x * 128 + c];
        ax0 += w0 * bf2f(v0 & 0xffffu) + w1 * bf2f(v1 & 0xffffu);
        ay0 += w0 * bf2f(v0 >> 16)     + w1 * bf2f(v1 >> 16);
        ax1 += w2 * bf2f(v2 & 0xffffu) + w3 * bf2f(v3 & 0xffffu);
        ay1 += w2 * bf2f(v2 >> 16)     + w3 * bf2f(v3 >> 16);
        ax2 += w4 * bf2f(v4 & 0xffffu) + w5 * bf2f(v5 & 0xffffu);
        ay2 += w4 * bf2f(v4 >> 16)     + w5 * bf2f(v5 >> 16);
        ax3 += w6 * bf2f(v6 & 0xffffu) + w7 * bf2f(v7 & 0xffffu);
        ay3 += w6 * bf2f(v6 >> 16)     + w7 * bf2f(v7 >> 16);
    }
    float ax = (ax0 + ax1) + (ax2 + ax3) + bias[c];
    float ay = (ay0 + ay1) + (ay2 + ay3) + bias[c + 1];
    if (RELU) { ax = fmaxf(ax, 0.f); ay = fmaxf(ay, 0.f); }
    unsigned int o = (unsigned int)f2bf(ax) | ((unsigned int)f2bf(ay) << 16);
    *(unsigned int*)&out[(size_t)node * 128 + c] = o;
}

// ---------------- Gather F=64 (bf16 h) + bias + log_softmax (fp32 out) -----
__global__ __launch_bounds__(256) void k_gather64_lsm(
        const int* __restrict__ rs, const int2* __restrict__ cv,
        const float* __restrict__ dis,
        const unsigned short* __restrict__ h, const float* __restrict__ bias,
        float* __restrict__ out, int n) {
    int node = (blockIdx.x * 256 + threadIdx.x) >> 6;
    int lane = threadIdx.x & 63;
    if (node >= n) return;
    float di = dis[node];
    float a0 = bf2f(h[(size_t)node * 64 + lane]) * di * di;
    float a1 = 0.f, a2 = 0.f, a3 = 0.f;
    int beg = rs[node], end = rs[node + 1];
    int last = end - 1;
    for (int j = beg; j < end; j += 8) {
        int2 c0 = cv[j];
        int2 c1 = cv[min(j + 1, last)];
        int2 c2 = cv[min(j + 2, last)];
        int2 c3 = cv[min(j + 3, last)];
        int2 c4 = cv[min(j + 4, last)];
        int2 c5 = cv[min(j + 5, last)];
        int2 c6 = cv[min(j + 6, last)];
        int2 c7 = cv[min(j + 7, last)];
        float w0 = __int_as_float(c0.y);
        float w1 = (j + 1 < end) ? __int_as_float(c1.y) : 0.f;
        float w2 = (j + 2 < end) ? __int_as_float(c2.y) : 0.f;
        float w3 = (j + 3 < end) ? __int_as_float(c3.y) : 0.f;
        float w4 = (j + 4 < end) ? __int_as_float(c4.y) : 0.f;
        float w5 = (j + 5 < end) ? __int_as_float(c5.y) : 0.f;
        float w6 = (j + 6 < end) ? __int_as_float(c6.y) : 0.f;
        float w7 = (j + 7 < end) ? __int_as_float(c7.y) : 0.f;
        float h0 = bf2f(h[(size_t)c0.x * 64 + lane]);
        float h1 = bf2f(h[(size_t)c1.x * 64 + lane]);
        float h2 = bf2f(h[(size_t)c2.x * 64 + lane]);
        float h3 = bf2f(h[(size_t)c3.x * 64 + lane]);
        float h4 = bf2f(h[(size_t)c4.x * 64 + lane]);
        float h5 = bf2f(h[(size_t)c5.x * 64 + lane]);
        float h6 = bf2f(h[(size_t)c6.x * 64 + lane]);
        float h7 = bf2f(h[(size_t)c7.x * 64 + lane]);
        a0 += w0 * h0 + w1 * h1;
        a1 += w2 * h2 + w3 * h3;
        a2 += w4 * h4 + w5 * h5;
        a3 += w6 * h6 + w7 * h7;
    }
    float v = (a0 + a1) + (a2 + a3) + bias[lane];
    float mm = v;
#pragma unroll
    for (int s = 32; s; s >>= 1) mm = fmaxf(mm, __shfl_xor(mm, s));
    float e = expf(v - mm);
    float sum = e;
#pragma unroll
    for (int s = 32; s; s >>= 1) sum += __shfl_xor(sum, s);
    out[(size_t)node * 64 + lane] = (v - mm) - logf(sum);
}

extern "C" void kernel_launch(void* const* d_in, const int* in_sizes, int n_in,
                              void* d_out, int out_size, void* d_ws, size_t ws_size,
                              hipStream_t stream) {
    constexpr int IN = 512, HID = 128, OUT = 64;
    const float* feats = (const float*)d_in[0];
    const int*   adj   = (const int*)d_in[1];
    const float* W1 = (const float*)d_in[2];
    const float* b1 = (const float*)d_in[3];
    const float* W2 = (const float*)d_in[4];
    const float* b2 = (const float*)d_in[5];
    const float* W3 = (const float*)d_in[6];
    const float* b3 = (const float*)d_in[7];
    float* out = (float*)d_out;

    const int n = in_sizes[0] / IN;      // 50000
    const int e = in_sizes[1] / 2;       // 800000
    const int* srcp = adj;
    const int* dstp = adj + e;

    // workspace layout
    char* ws = (char*)d_ws;
    int*   deg  = (int*)ws;                    ws += (size_t)n * 4;
    float* dis  = (float*)ws;                  ws += (size_t)n * 4;
    int*   incl = (int*)ws;                    ws += (size_t)n * 4;
    int*   bsum = (int*)ws;                    ws += 256 * 4;
    int*   rs   = (int*)ws;                    ws += (size_t)(n + 1) * 4 + 4;
    int*   curs = (int*)ws;                    ws += (size_t)n * 4;
    int2*  cv   = (int2*)ws;                   ws += (size_t)e * 8;
    unsigned short* Wt1 = (unsigned short*)ws; ws += (size_t)IN * HID * 2;
    unsigned short* Wt2 = (unsigned short*)ws; ws += (size_t)HID * HID * 2;
    unsigned short* Wt3 = (unsigned short*)ws; ws += (size_t)HID * OUT * 2;
    unsigned short* hb  = (unsigned short*)ws; ws += (size_t)n * HID * 2;
    unsigned short* xb  = (unsigned short*)ws; ws += (size_t)n * HID * 2;

    const int nb_n = (n + 255) / 256;
    const int nb_e = (e + 255) / 256;
    const int nb_g = (n + 63) / 64;          // reg-GEMM blocks (64 rows/block)
    const int nb_w = (n * 64 + 255) / 256;   // 1 wave/node kernels

    // ---- build CSR (by dst) + symmetric norm
    k_zero_i32<<<nb_n, 256, 0, stream>>>(deg, n);
    k_deg_count<<<nb_e, 256, 0, stream>>>(dstp, deg, e);
    k_dis<<<nb_n, 256, 0, stream>>>(deg, dis, n);
    k_scan_block<<<nb_n, 256, 0, stream>>>(deg, incl, bsum, n);
    k_scan_bsum<<<1, 256, 0, stream>>>(bsum, nb_n);
    k_scan_final<<<nb_n, 256, 0, stream>>>(deg, incl, bsum, rs, curs, n, e);
    k_csr_fill<<<nb_e, 256, 0, stream>>>(srcp, dstp, dis, curs, cv, e);

    // ---- weight transposes (fp32 -> bf16, [K][F] -> [F][K])
    k_wt<<<(IN * HID + 255) / 256, 256, 0, stream>>>(W1, Wt1, IN, HID);
    k_wt<<<(HID * HID + 255) / 256, 256, 0, stream>>>(W2, Wt2, HID, HID);
    k_wt<<<(HID * OUT + 255) / 256, 256, 0, stream>>>(W3, Wt3, HID, OUT);

    // ---- layer 1: 512 -> 128, gather + bias + relu
    k_gemm_reg<IN, HID, false, 2><<<nb_g, 256, 0, stream>>>(feats, Wt1, hb, n);
    k_gather128<true><<<nb_w, 256, 0, stream>>>(rs, cv, dis, hb, b1, xb, n);

    // ---- layer 2: 128 -> 128, gather + bias + relu
    k_gemm_reg<HID, HID, true, 4><<<nb_g, 256, 0, stream>>>(xb, Wt2, hb, n);
    k_gather128<true><<<nb_w, 256, 0, stream>>>(rs, cv, dis, hb, b2, xb, n);

    // ---- layer 3: 128 -> 64, gather + bias + log_softmax
    k_gemm_reg<HID, OUT, true, 4><<<nb_g, 256, 0, stream>>>(xb, Wt3, hb, n);
    k_gather64_lsm<<<nb_w, 256, 0, stream>>>(rs, cv, dis, hb, b3, out, n);
}

// Round 7
// 427.353 us; speedup vs baseline: 1.1700x; 1.1700x over previous
//
#include <hip/hip_runtime.h>
#include <hip/hip_bf16.h>
#include <math.h>

// ---------------------------------------------------------------------------
// GCN 3-layer forward. R7: GEMM = whole-B-in-LDS (padded rows, conflict-floor
// ds_read_b128), barrier-free K-loop for layers 2/3, 4 K-chunks for layer 1.
// A loads are per-lane global->reg (no barrier dependency). Packed int2 CSR +
// 8-way MLP gathers kept.
// ---------------------------------------------------------------------------

using short8  = __attribute__((ext_vector_type(8))) short;
using floatx4 = __attribute__((ext_vector_type(4))) float;

__device__ inline float bf2f(unsigned int u16) {
    union { unsigned int i; float f; } x; x.i = u16 << 16; return x.f;
}
__device__ inline unsigned short f2bf(float f) {
    union { float f; unsigned int i; } x; x.f = f;
    unsigned int lsb = (x.i >> 16) & 1u;
    return (unsigned short)((x.i + 0x7fffu + lsb) >> 16);
}

// ---------------- CSR build ----------------
__global__ void k_zero_i32(int* p, int n) {
    int i = blockIdx.x * 256 + threadIdx.x;
    if (i < n) p[i] = 0;
}

__global__ void k_deg_count(const int* __restrict__ dst, int* deg, int e) {
    int i = blockIdx.x * 256 + threadIdx.x;
    if (i < e) atomicAdd(&deg[dst[i]], 1);
}

__global__ void k_dis(const int* __restrict__ deg, float* dis, int n) {
    int i = blockIdx.x * 256 + threadIdx.x;
    if (i < n) dis[i] = rsqrtf((float)(deg[i] + 1));   // +1 self loop
}

__global__ void k_scan_block(const int* __restrict__ deg, int* incl, int* bsum, int n) {
    __shared__ int s[256];
    int tid = threadIdx.x;
    int i = blockIdx.x * 256 + tid;
    int v = (i < n) ? deg[i] : 0;
    s[tid] = v;
    __syncthreads();
    for (int off = 1; off < 256; off <<= 1) {
        int t = (tid >= off) ? s[tid - off] : 0;
        __syncthreads();
        s[tid] += t;
        __syncthreads();
    }
    if (i < n) incl[i] = s[tid];
    if (tid == 255) bsum[blockIdx.x] = s[255];
}

__global__ void k_scan_bsum(int* bsum, int nb) {   // single block, nb <= 256
    __shared__ int s[256];
    int tid = threadIdx.x;
    s[tid] = (tid < nb) ? bsum[tid] : 0;
    __syncthreads();
    for (int off = 1; off < 256; off <<= 1) {
        int t = (tid >= off) ? s[tid - off] : 0;
        __syncthreads();
        s[tid] += t;
        __syncthreads();
    }
    if (tid < nb) bsum[tid] = s[tid];
}

__global__ void k_scan_final(const int* __restrict__ deg, const int* __restrict__ incl,
                             const int* __restrict__ bsum, int* row_start, int* cursor,
                             int n, int e) {
    int i = blockIdx.x * 256 + threadIdx.x;
    if (i == 0) row_start[n] = e;
    if (i >= n) return;
    int base = (blockIdx.x > 0) ? bsum[blockIdx.x - 1] : 0;
    int excl = base + incl[i] - deg[i];
    row_start[i] = excl;
    cursor[i] = excl;
}

// packed (col, val) per edge: one 8B store -> one cache line touched
__global__ void k_csr_fill(const int* __restrict__ src, const int* __restrict__ dst,
                           const float* __restrict__ dis, int* cursor,
                           int2* __restrict__ cv, int e) {
    int i = blockIdx.x * 256 + threadIdx.x;
    if (i >= e) return;
    int s = src[i], d = dst[i];
    int pos = atomicAdd(&cursor[d], 1);
    float w = dis[s] * dis[d];
    cv[pos] = make_int2(s, __float_as_int(w));
}

// ---------------- W transpose + bf16 cast: Wt[f][k] = bf16(W[k][f]) --------
__global__ void k_wt(const float* __restrict__ W, unsigned short* __restrict__ Wt,
                     int K, int F) {
    int i = blockIdx.x * 256 + threadIdx.x;
    if (i >= K * F) return;
    int k = i / F, f = i % F;
    Wt[(size_t)f * K + k] = f2bf(W[i]);
}

// ---------------- GEMM: whole-B-in-LDS, barrier-light ----------------------
// C[n x BN](bf16) = A[n x K] @ Wt^T.  Wt = [BN x K] bf16.
// Block = 256 thr = 4 waves; wave wv owns rows [blk*64 + wv*16, +16) x BN.
// B staged to LDS in KC=128 chunks (once total for K=128). Padded row stride
// (KC+8 ushorts = 272 B, 16B-aligned) puts ds_read_b128 at the conflict floor.
// A: per-lane global->reg, unrolled chunk body -> loads hoisted by compiler.
template <int K, int BN, bool A_BF16>
__global__ __launch_bounds__(256) void k_gemm_bl(const void* __restrict__ Av,
                                                 const unsigned short* __restrict__ Wt,
                                                 unsigned short* __restrict__ C, int n) {
    constexpr int KC = 128;                   // K-chunk staged per barrier
    constexpr int NCH = K / KC;
    constexpr int NT = BN / 16;
    constexpr int LDB = KC + 8;               // padded (272 B stride)
    __shared__ unsigned short Bs[BN][LDB];    // 34.8 KB (BN=128) / 17.4 KB (64)

    const int tid = threadIdx.x;
    const int wv = tid >> 6;
    const int lane = tid & 63;
    const int m = lane & 15;
    const int quad = lane >> 4;
    const int rowb = blockIdx.x * 64 + wv * 16;
    const int r0 = min(rowb + m, n - 1);      // clamped loads; stores guarded

    floatx4 acc[NT] = {};

    for (int ch = 0; ch < NCH; ++ch) {
        const int kc = ch * KC;
        if (ch > 0) __syncthreads();          // Bs reuse: prev reads done
        // ---- stage B chunk: BN x KC bf16, coalesced uint4
#pragma unroll
        for (int l = 0; l < (BN * KC) / (256 * 8); ++l) {
            int id = tid + l * 256;
            int row = id / (KC / 8);
            int p = id % (KC / 8);
            *(uint4*)&Bs[row][p * 8] = *(const uint4*)&Wt[(size_t)row * K + kc + p * 8];
        }
        __syncthreads();

#pragma unroll
        for (int ki = 0; ki < KC / 32; ++ki) {
            const int k = kc + ki * 32;
            short8 a;
            if constexpr (A_BF16) {
                const unsigned short* A = (const unsigned short*)Av;
                a = *(const short8*)&A[(size_t)r0 * K + k + quad * 8];
            } else {
                const float* A = (const float*)Av;
                float4 f0 = *(const float4*)&A[(size_t)r0 * K + k + quad * 8];
                float4 f1 = *(const float4*)&A[(size_t)r0 * K + k + quad * 8 + 4];
                a[0] = (short)f2bf(f0.x); a[1] = (short)f2bf(f0.y);
                a[2] = (short)f2bf(f0.z); a[3] = (short)f2bf(f0.w);
                a[4] = (short)f2bf(f1.x); a[5] = (short)f2bf(f1.y);
                a[6] = (short)f2bf(f1.z); a[7] = (short)f2bf(f1.w);
            }
#pragma unroll
            for (int t = 0; t < NT; ++t) {
                short8 b = *(const short8*)&Bs[t * 16 + m][ki * 32 + quad * 8];
                acc[t] = __builtin_amdgcn_mfma_f32_16x16x32_bf16(a, b, acc[t], 0, 0, 0);
            }
        }
    }

    // C/D layout: col = lane&15, row = quad*4 + reg
#pragma unroll
    for (int t = 0; t < NT; ++t) {
        int cc = t * 16 + m;
#pragma unroll
        for (int r = 0; r < 4; ++r) {
            int ga = rowb + quad * 4 + r;
            if (ga < n) C[(size_t)ga * BN + cc] = f2bf(acc[t][r]);
        }
    }
}

// ---------------- Gather F=128 (bf16 h/out), fused bias(+relu) -------------
// 8-way MLP: 8 independent h-row loads per round (clamped idx, zeroed weight).
template <bool RELU>
__global__ __launch_bounds__(256) void k_gather128(
        const int* __restrict__ rs, const int2* __restrict__ cv,
        const float* __restrict__ dis,
        const unsigned short* __restrict__ h, const float* __restrict__ bias,
        unsigned short* __restrict__ out, int n) {
    int node = (blockIdx.x * 256 + threadIdx.x) >> 6;
    int lane = threadIdx.x & 63;
    if (node >= n) return;
    int c = lane * 2;
    float di = dis[node];
    unsigned int hv = *(const unsigned int*)&h[(size_t)node * 128 + c];
    float ax0 = bf2f(hv & 0xffffu) * di * di;
    float ay0 = bf2f(hv >> 16) * di * di;
    float ax1 = 0.f, ay1 = 0.f, ax2 = 0.f, ay2 = 0.f, ax3 = 0.f, ay3 = 0.f;
    int beg = rs[node], end = rs[node + 1];
    int last = end - 1;
    for (int j = beg; j < end; j += 8) {
        int2 c0 = cv[j];
        int2 c1 = cv[min(j + 1, last)];
        int2 c2 = cv[min(j + 2, last)];
        int2 c3 = cv[min(j + 3, last)];
        int2 c4 = cv[min(j + 4, last)];
        int2 c5 = cv[min(j + 5, last)];
        int2 c6 = cv[min(j + 6, last)];
        int2 c7 = cv[min(j + 7, last)];
        float w0 = __int_as_float(c0.y);
        float w1 = (j + 1 < end) ? __int_as_float(c1.y) : 0.f;
        float w2 = (j + 2 < end) ? __int_as_float(c2.y) : 0.f;
        float w3 = (j + 3 < end) ? __int_as_float(c3.y) : 0.f;
        float w4 = (j + 4 < end) ? __int_as_float(c4.y) : 0.f;
        float w5 = (j + 5 < end) ? __int_as_float(c5.y) : 0.f;
        float w6 = (j + 6 < end) ? __int_as_float(c6.y) : 0.f;
        float w7 = (j + 7 < end) ? __int_as_float(c7.y) : 0.f;
        unsigned int v0 = *(const unsigned int*)&h[(size_t)c0.x * 128 + c];
        unsigned int v1 = *(const unsigned int*)&h[(size_t)c1.x * 128 + c];
        unsigned int v2 = *(const unsigned int*)&h[(size_t)c2.x * 128 + c];
        unsigned int v3 = *(const unsigned int*)&h[(size_t)c3.x * 128 + c];
        unsigned int v4 = *(const unsigned int*)&h[(size_t)c4.x * 128 + c];
        unsigned int v5 = *(const unsigned int*)&h[(size_t)c5.x * 128 + c];
        unsigned int v6 = *(const unsigned int*)&h[(size_t)c6.x * 128 + c];
        unsigned int v7 = *(const unsigned int*)&h[(size_t)c7.x * 128 + c];
        ax0 += w0 * bf2f(v0 & 0xffffu) + w1 * bf2f(v1 & 0xffffu);
        ay0 += w0 * bf2f(v0 >> 16)     + w1 * bf2f(v1 >> 16);
        ax1 += w2 * bf2f(v2 & 0xffffu) + w3 * bf2f(v3 & 0xffffu);
        ay1 += w2 * bf2f(v2 >> 16)     + w3 * bf2f(v3 >> 16);
        ax2 += w4 * bf2f(v4 & 0xffffu) + w5 * bf2f(v5 & 0xffffu);
        ay2 += w4 * bf2f(v4 >> 16)     + w5 * bf2f(v5 >> 16);
        ax3 += w6 * bf2f(v6 & 0xffffu) + w7 * bf2f(v7 & 0xffffu);
        ay3 += w6 * bf2f(v6 >> 16)     + w7 * bf2f(v7 >> 16);
    }
    float ax = (ax0 + ax1) + (ax2 + ax3) + bias[c];
    float ay = (ay0 + ay1) + (ay2 + ay3) + bias[c + 1];
    if (RELU) { ax = fmaxf(ax, 0.f); ay = fmaxf(ay, 0.f); }
    unsigned int o = (unsigned int)f2bf(ax) | ((unsigned int)f2bf(ay) << 16);
    *(unsigned int*)&out[(size_t)node * 128 + c] = o;
}

// ---------------- Gather F=64 (bf16 h) + bias + log_softmax (fp32 out) -----
__global__ __launch_bounds__(256) void k_gather64_lsm(
        const int* __restrict__ rs, const int2* __restrict__ cv,
        const float* __restrict__ dis,
        const unsigned short* __restrict__ h, const float* __restrict__ bias,
        float* __restrict__ out, int n) {
    int node = (blockIdx.x * 256 + threadIdx.x) >> 6;
    int lane = threadIdx.x & 63;
    if (node >= n) return;
    float di = dis[node];
    float a0 = bf2f(h[(size_t)node * 64 + lane]) * di * di;
    float a1 = 0.f, a2 = 0.f, a3 = 0.f;
    int beg = rs[node], end = rs[node + 1];
    int last = end - 1;
    for (int j = beg; j < end; j += 8) {
        int2 c0 = cv[j];
        int2 c1 = cv[min(j + 1, last)];
        int2 c2 = cv[min(j + 2, last)];
        int2 c3 = cv[min(j + 3, last)];
        int2 c4 = cv[min(j + 4, last)];
        int2 c5 = cv[min(j + 5, last)];
        int2 c6 = cv[min(j + 6, last)];
        int2 c7 = cv[min(j + 7, last)];
        float w0 = __int_as_float(c0.y);
        float w1 = (j + 1 < end) ? __int_as_float(c1.y) : 0.f;
        float w2 = (j + 2 < end) ? __int_as_float(c2.y) : 0.f;
        float w3 = (j + 3 < end) ? __int_as_float(c3.y) : 0.f;
        float w4 = (j + 4 < end) ? __int_as_float(c4.y) : 0.f;
        float w5 = (j + 5 < end) ? __int_as_float(c5.y) : 0.f;
        float w6 = (j + 6 < end) ? __int_as_float(c6.y) : 0.f;
        float w7 = (j + 7 < end) ? __int_as_float(c7.y) : 0.f;
        float h0 = bf2f(h[(size_t)c0.x * 64 + lane]);
        float h1 = bf2f(h[(size_t)c1.x * 64 + lane]);
        float h2 = bf2f(h[(size_t)c2.x * 64 + lane]);
        float h3 = bf2f(h[(size_t)c3.x * 64 + lane]);
        float h4 = bf2f(h[(size_t)c4.x * 64 + lane]);
        float h5 = bf2f(h[(size_t)c5.x * 64 + lane]);
        float h6 = bf2f(h[(size_t)c6.x * 64 + lane]);
        float h7 = bf2f(h[(size_t)c7.x * 64 + lane]);
        a0 += w0 * h0 + w1 * h1;
        a1 += w2 * h2 + w3 * h3;
        a2 += w4 * h4 + w5 * h5;
        a3 += w6 * h6 + w7 * h7;
    }
    float v = (a0 + a1) + (a2 + a3) + bias[lane];
    float mm = v;
#pragma unroll
    for (int s = 32; s; s >>= 1) mm = fmaxf(mm, __shfl_xor(mm, s));
    float e = expf(v - mm);
    float sum = e;
#pragma unroll
    for (int s = 32; s; s >>= 1) sum += __shfl_xor(sum, s);
    out[(size_t)node * 64 + lane] = (v - mm) - logf(sum);
}

extern "C" void kernel_launch(void* const* d_in, const int* in_sizes, int n_in,
                              void* d_out, int out_size, void* d_ws, size_t ws_size,
                              hipStream_t stream) {
    constexpr int IN = 512, HID = 128, OUT = 64;
    const float* feats = (const float*)d_in[0];
    const int*   adj   = (const int*)d_in[1];
    const float* W1 = (const float*)d_in[2];
    const float* b1 = (const float*)d_in[3];
    const float* W2 = (const float*)d_in[4];
    const float* b2 = (const float*)d_in[5];
    const float* W3 = (const float*)d_in[6];
    const float* b3 = (const float*)d_in[7];
    float* out = (float*)d_out;

    const int n = in_sizes[0] / IN;      // 50000
    const int e = in_sizes[1] / 2;       // 800000
    const int* srcp = adj;
    const int* dstp = adj + e;

    // workspace layout
    char* ws = (char*)d_ws;
    int*   deg  = (int*)ws;                    ws += (size_t)n * 4;
    float* dis  = (float*)ws;                  ws += (size_t)n * 4;
    int*   incl = (int*)ws;                    ws += (size_t)n * 4;
    int*   bsum = (int*)ws;                    ws += 256 * 4;
    int*   rs   = (int*)ws;                    ws += (size_t)(n + 1) * 4 + 4;
    int*   curs = (int*)ws;                    ws += (size_t)n * 4;
    int2*  cv   = (int2*)ws;                   ws += (size_t)e * 8;
    unsigned short* Wt1 = (unsigned short*)ws; ws += (size_t)IN * HID * 2;
    unsigned short* Wt2 = (unsigned short*)ws; ws += (size_t)HID * HID * 2;
    unsigned short* Wt3 = (unsigned short*)ws; ws += (size_t)HID * OUT * 2;
    unsigned short* hb  = (unsigned short*)ws; ws += (size_t)n * HID * 2;
    unsigned short* xb  = (unsigned short*)ws; ws += (size_t)n * HID * 2;

    const int nb_n = (n + 255) / 256;
    const int nb_e = (e + 255) / 256;
    const int nb_g = (n + 63) / 64;          // GEMM blocks (64 rows/block)
    const int nb_w = (n * 64 + 255) / 256;   // 1 wave/node kernels

    // ---- build CSR (by dst) + symmetric norm
    k_zero_i32<<<nb_n, 256, 0, stream>>>(deg, n);
    k_deg_count<<<nb_e, 256, 0, stream>>>(dstp, deg, e);
    k_dis<<<nb_n, 256, 0, stream>>>(deg, dis, n);
    k_scan_block<<<nb_n, 256, 0, stream>>>(deg, incl, bsum, n);
    k_scan_bsum<<<1, 256, 0, stream>>>(bsum, nb_n);
    k_scan_final<<<nb_n, 256, 0, stream>>>(deg, incl, bsum, rs, curs, n, e);
    k_csr_fill<<<nb_e, 256, 0, stream>>>(srcp, dstp, dis, curs, cv, e);

    // ---- weight transposes (fp32 -> bf16, [K][F] -> [F][K])
    k_wt<<<(IN * HID + 255) / 256, 256, 0, stream>>>(W1, Wt1, IN, HID);
    k_wt<<<(HID * HID + 255) / 256, 256, 0, stream>>>(W2, Wt2, HID, HID);
    k_wt<<<(HID * OUT + 255) / 256, 256, 0, stream>>>(W3, Wt3, HID, OUT);

    // ---- layer 1: 512 -> 128, gather + bias + relu
    k_gemm_bl<IN, HID, false><<<nb_g, 256, 0, stream>>>(feats, Wt1, hb, n);
    k_gather128<true><<<nb_w, 256, 0, stream>>>(rs, cv, dis, hb, b1, xb, n);

    // ---- layer 2: 128 -> 128, gather + bias + relu
    k_gemm_bl<HID, HID, true><<<nb_g, 256, 0, stream>>>(xb, Wt2, hb, n);
    k_gather128<true><<<nb_w, 256, 0, stream>>>(rs, cv, dis, hb, b2, xb, n);

    // ---- layer 3: 128 -> 64, gather + bias + log_softmax
    k_gemm_bl<HID, OUT, true><<<nb_g, 256, 0, stream>>>(xb, Wt3, hb, n);
    k_gather64_lsm<<<nb_w, 256, 0, stream>>>(rs, cv, dis, hb, b3, out, n);
}

// Round 8
// 399.481 us; speedup vs baseline: 1.2517x; 1.0698x over previous
//
#include <hip/hip_runtime.h>
#include <hip/hip_bf16.h>
#include <math.h>

// ---------------------------------------------------------------------------
// GCN 3-layer forward. R8: norm folded into features — GEMM epilogue stores
// hs = dis*h (bf16); out[d] = dis[d]*(hs[d] + sum hs[src]). Edge payload is
// a bare uint16 col (1.6 MB, L2-resident -> scatter writes coalesce in L2).
// Whole-B-LDS GEMM (R7) + 8-way MLP gathers kept.
// ---------------------------------------------------------------------------

using short8  = __attribute__((ext_vector_type(8))) short;
using floatx4 = __attribute__((ext_vector_type(4))) float;

__device__ inline float bf2f(unsigned int u16) {
    union { unsigned int i; float f; } x; x.i = u16 << 16; return x.f;
}
__device__ inline unsigned short f2bf(float f) {
    union { float f; unsigned int i; } x; x.f = f;
    unsigned int lsb = (x.i >> 16) & 1u;
    return (unsigned short)((x.i + 0x7fffu + lsb) >> 16);
}

// ---------------- CSR build ----------------
__global__ void k_zero_i32(int* p, int n) {
    int i = blockIdx.x * 256 + threadIdx.x;
    if (i < n) p[i] = 0;
}

__global__ void k_deg_count(const int* __restrict__ dst, int* deg, int e) {
    int i = blockIdx.x * 256 + threadIdx.x;
    if (i < e) atomicAdd(&deg[dst[i]], 1);
}

__global__ void k_dis(const int* __restrict__ deg, float* dis, int n) {
    int i = blockIdx.x * 256 + threadIdx.x;
    if (i < n) dis[i] = rsqrtf((float)(deg[i] + 1));   // +1 self loop
}

__global__ void k_scan_block(const int* __restrict__ deg, int* incl, int* bsum, int n) {
    __shared__ int s[256];
    int tid = threadIdx.x;
    int i = blockIdx.x * 256 + tid;
    int v = (i < n) ? deg[i] : 0;
    s[tid] = v;
    __syncthreads();
    for (int off = 1; off < 256; off <<= 1) {
        int t = (tid >= off) ? s[tid - off] : 0;
        __syncthreads();
        s[tid] += t;
        __syncthreads();
    }
    if (i < n) incl[i] = s[tid];
    if (tid == 255) bsum[blockIdx.x] = s[255];
}

__global__ void k_scan_bsum(int* bsum, int nb) {   // single block, nb <= 256
    __shared__ int s[256];
    int tid = threadIdx.x;
    s[tid] = (tid < nb) ? bsum[tid] : 0;
    __syncthreads();
    for (int off = 1; off < 256; off <<= 1) {
        int t = (tid >= off) ? s[tid - off] : 0;
        __syncthreads();
        s[tid] += t;
        __syncthreads();
    }
    if (tid < nb) bsum[tid] = s[tid];
}

__global__ void k_scan_final(const int* __restrict__ deg, const int* __restrict__ incl,
                             const int* __restrict__ bsum, int* row_start, int* cursor,
                             int n, int e) {
    int i = blockIdx.x * 256 + threadIdx.x;
    if (i == 0) row_start[n] = e;
    if (i >= n) return;
    int base = (blockIdx.x > 0) ? bsum[blockIdx.x - 1] : 0;
    int excl = base + incl[i] - deg[i];
    row_start[i] = excl;
    cursor[i] = excl;
}

// 2 B payload per edge: cs[pos] = src node id (uint16, n < 65536)
__global__ void k_csr_fill16(const int* __restrict__ src, const int* __restrict__ dst,
                             int* cursor, unsigned short* __restrict__ cs, int e) {
    int i = blockIdx.x * 256 + threadIdx.x;
    if (i >= e) return;
    int s = src[i], d = dst[i];
    int pos = atomicAdd(&cursor[d], 1);
    cs[pos] = (unsigned short)s;
}

// ---------------- all W transposes + bf16 cast in one dispatch -------------
__global__ void k_wt_all(const float* __restrict__ W1, const float* __restrict__ W2,
                         const float* __restrict__ W3,
                         unsigned short* __restrict__ Wt1, unsigned short* __restrict__ Wt2,
                         unsigned short* __restrict__ Wt3) {
    int i = blockIdx.x * 256 + threadIdx.x;
    if (i < 512 * 128) {
        int k = i / 128, f = i % 128;
        Wt1[(size_t)f * 512 + k] = f2bf(W1[i]);
    } else if (i < 512 * 128 + 128 * 128) {
        int j = i - 512 * 128;
        int k = j / 128, f = j % 128;
        Wt2[(size_t)f * 128 + k] = f2bf(W2[j]);
    } else if (i < 512 * 128 + 128 * 128 + 128 * 64) {
        int j = i - (512 * 128 + 128 * 128);
        int k = j / 64, f = j % 64;
        Wt3[(size_t)f * 128 + k] = f2bf(W3[j]);
    }
}

// ---------------- GEMM: whole-B-in-LDS, epilogue scales by dis[row] --------
// C[n x BN](bf16) = dis[row] * (A[n x K] @ Wt^T).  Wt = [BN x K] bf16.
template <int K, int BN, bool A_BF16>
__global__ __launch_bounds__(256) void k_gemm_bl(const void* __restrict__ Av,
                                                 const unsigned short* __restrict__ Wt,
                                                 const float* __restrict__ dis,
                                                 unsigned short* __restrict__ C, int n) {
    constexpr int KC = 128;                   // K-chunk staged per barrier
    constexpr int NCH = K / KC;
    constexpr int NT = BN / 16;
    constexpr int LDB = KC + 8;               // padded (272 B stride)
    __shared__ unsigned short Bs[BN][LDB];

    const int tid = threadIdx.x;
    const int wv = tid >> 6;
    const int lane = tid & 63;
    const int m = lane & 15;
    const int quad = lane >> 4;
    const int rowb = blockIdx.x * 64 + wv * 16;
    const int r0 = min(rowb + m, n - 1);      // clamped loads; stores guarded

    floatx4 acc[NT] = {};

    for (int ch = 0; ch < NCH; ++ch) {
        const int kc = ch * KC;
        if (ch > 0) __syncthreads();
#pragma unroll
        for (int l = 0; l < (BN * KC) / (256 * 8); ++l) {
            int id = tid + l * 256;
            int row = id / (KC / 8);
            int p = id % (KC / 8);
            *(uint4*)&Bs[row][p * 8] = *(const uint4*)&Wt[(size_t)row * K + kc + p * 8];
        }
        __syncthreads();

#pragma unroll
        for (int ki = 0; ki < KC / 32; ++ki) {
            const int k = kc + ki * 32;
            short8 a;
            if constexpr (A_BF16) {
                const unsigned short* A = (const unsigned short*)Av;
                a = *(const short8*)&A[(size_t)r0 * K + k + quad * 8];
            } else {
                const float* A = (const float*)Av;
                float4 f0 = *(const float4*)&A[(size_t)r0 * K + k + quad * 8];
                float4 f1 = *(const float4*)&A[(size_t)r0 * K + k + quad * 8 + 4];
                a[0] = (short)f2bf(f0.x); a[1] = (short)f2bf(f0.y);
                a[2] = (short)f2bf(f0.z); a[3] = (short)f2bf(f0.w);
                a[4] = (short)f2bf(f1.x); a[5] = (short)f2bf(f1.y);
                a[6] = (short)f2bf(f1.z); a[7] = (short)f2bf(f1.w);
            }
#pragma unroll
            for (int t = 0; t < NT; ++t) {
                short8 b = *(const short8*)&Bs[t * 16 + m][ki * 32 + quad * 8];
                acc[t] = __builtin_amdgcn_mfma_f32_16x16x32_bf16(a, b, acc[t], 0, 0, 0);
            }
        }
    }

    // C/D layout: col = lane&15, row = quad*4 + reg; scale by dis[row]
#pragma unroll
    for (int r = 0; r < 4; ++r) {
        int ga = rowb + quad * 4 + r;
        if (ga < n) {
            float dr = dis[ga];
#pragma unroll
            for (int t = 0; t < NT; ++t)
                C[(size_t)ga * BN + t * 16 + m] = f2bf(acc[t][r] * dr);
        }
    }
}

// ---------------- Gather F=128: out = ep(dis[d]*(hs[d]+sum hs[s]) + b) -----
// 8-way MLP with uint16 col stream and 0/1 tail masks.
template <bool RELU>
__global__ __launch_bounds__(256) void k_gather128(
        const int* __restrict__ rs, const unsigned short* __restrict__ cs,
        const float* __restrict__ dis,
        const unsigned short* __restrict__ h, const float* __restrict__ bias,
        unsigned short* __restrict__ out, int n) {
    int node = (blockIdx.x * 256 + threadIdx.x) >> 6;
    int lane = threadIdx.x & 63;
    if (node >= n) return;
    int c = lane * 2;
    unsigned int hv = *(const unsigned int*)&h[(size_t)node * 128 + c];
    float ax0 = bf2f(hv & 0xffffu);
    float ay0 = bf2f(hv >> 16);
    float ax1 = 0.f, ay1 = 0.f, ax2 = 0.f, ay2 = 0.f, ax3 = 0.f, ay3 = 0.f;
    int beg = rs[node], end = rs[node + 1];
    int last = end - 1;
    for (int j = beg; j < end; j += 8) {
        int s0 = cs[j];
        int s1 = cs[min(j + 1, last)];
        int s2 = cs[min(j + 2, last)];
        int s3 = cs[min(j + 3, last)];
        int s4 = cs[min(j + 4, last)];
        int s5 = cs[min(j + 5, last)];
        int s6 = cs[min(j + 6, last)];
        int s7 = cs[min(j + 7, last)];
        float w1 = (j + 1 < end) ? 1.f : 0.f;
        float w2 = (j + 2 < end) ? 1.f : 0.f;
        float w3 = (j + 3 < end) ? 1.f : 0.f;
        float w4 = (j + 4 < end) ? 1.f : 0.f;
        float w5 = (j + 5 < end) ? 1.f : 0.f;
        float w6 = (j + 6 < end) ? 1.f : 0.f;
        float w7 = (j + 7 < end) ? 1.f : 0.f;
        unsigned int v0 = *(const unsigned int*)&h[(size_t)s0 * 128 + c];
        unsigned int v1 = *(const unsigned int*)&h[(size_t)s1 * 128 + c];
        unsigned int v2 = *(const unsigned int*)&h[(size_t)s2 * 128 + c];
        unsigned int v3 = *(const unsigned int*)&h[(size_t)s3 * 128 + c];
        unsigned int v4 = *(const unsigned int*)&h[(size_t)s4 * 128 + c];
        unsigned int v5 = *(const unsigned int*)&h[(size_t)s5 * 128 + c];
        unsigned int v6 = *(const unsigned int*)&h[(size_t)s6 * 128 + c];
        unsigned int v7 = *(const unsigned int*)&h[(size_t)s7 * 128 + c];
        ax0 += bf2f(v0 & 0xffffu) + w1 * bf2f(v1 & 0xffffu);
        ay0 += bf2f(v0 >> 16)     + w1 * bf2f(v1 >> 16);
        ax1 += w2 * bf2f(v2 & 0xffffu) + w3 * bf2f(v3 & 0xffffu);
        ay1 += w2 * bf2f(v2 >> 16)     + w3 * bf2f(v3 >> 16);
        ax2 += w4 * bf2f(v4 & 0xffffu) + w5 * bf2f(v5 & 0xffffu);
        ay2 += w4 * bf2f(v4 >> 16)     + w5 * bf2f(v5 >> 16);
        ax3 += w6 * bf2f(v6 & 0xffffu) + w7 * bf2f(v7 & 0xffffu);
        ay3 += w6 * bf2f(v6 >> 16)     + w7 * bf2f(v7 >> 16);
    }
    float di = dis[node];
    float ax = ((ax0 + ax1) + (ax2 + ax3)) * di + bias[c];
    float ay = ((ay0 + ay1) + (ay2 + ay3)) * di + bias[c + 1];
    if (RELU) { ax = fmaxf(ax, 0.f); ay = fmaxf(ay, 0.f); }
    unsigned int o = (unsigned int)f2bf(ax) | ((unsigned int)f2bf(ay) << 16);
    *(unsigned int*)&out[(size_t)node * 128 + c] = o;
}

// ---------------- Gather F=64 + bias + log_softmax (fp32 out) --------------
__global__ __launch_bounds__(256) void k_gather64_lsm(
        const int* __restrict__ rs, const unsigned short* __restrict__ cs,
        const float* __restrict__ dis,
        const unsigned short* __restrict__ h, const float* __restrict__ bias,
        float* __restrict__ out, int n) {
    int node = (blockIdx.x * 256 + threadIdx.x) >> 6;
    int lane = threadIdx.x & 63;
    if (node >= n) return;
    float a0 = bf2f(h[(size_t)node * 64 + lane]);
    float a1 = 0.f, a2 = 0.f, a3 = 0.f;
    int beg = rs[node], end = rs[node + 1];
    int last = end - 1;
    for (int j = beg; j < end; j += 8) {
        int s0 = cs[j];
        int s1 = cs[min(j + 1, last)];
        int s2 = cs[min(j + 2, last)];
        int s3 = cs[min(j + 3, last)];
        int s4 = cs[min(j + 4, last)];
        int s5 = cs[min(j + 5, last)];
        int s6 = cs[min(j + 6, last)];
        int s7 = cs[min(j + 7, last)];
        float w1 = (j + 1 < end) ? 1.f : 0.f;
        float w2 = (j + 2 < end) ? 1.f : 0.f;
        float w3 = (j + 3 < end) ? 1.f : 0.f;
        float w4 = (j + 4 < end) ? 1.f : 0.f;
        float w5 = (j + 5 < end) ? 1.f : 0.f;
        float w6 = (j + 6 < end) ? 1.f : 0.f;
        float w7 = (j + 7 < end) ? 1.f : 0.f;
        float h0 = bf2f(h[(size_t)s0 * 64 + lane]);
        float h1 = bf2f(h[(size_t)s1 * 64 + lane]);
        float h2 = bf2f(h[(size_t)s2 * 64 + lane]);
        float h3 = bf2f(h[(size_t)s3 * 64 + lane]);
        float h4 = bf2f(h[(size_t)s4 * 64 + lane]);
        float h5 = bf2f(h[(size_t)s5 * 64 + lane]);
        float h6 = bf2f(h[(size_t)s6 * 64 + lane]);
        float h7 = bf2f(h[(size_t)s7 * 64 + lane]);
        a0 += h0 + w1 * h1;
        a1 += w2 * h2 + w3 * h3;
        a2 += w4 * h4 + w5 * h5;
        a3 += w6 * h6 + w7 * h7;
    }
    float v = ((a0 + a1) + (a2 + a3)) * dis[node] + bias[lane];
    float mm = v;
#pragma unroll
    for (int s = 32; s; s >>= 1) mm = fmaxf(mm, __shfl_xor(mm, s));
    float e = expf(v - mm);
    float sum = e;
#pragma unroll
    for (int s = 32; s; s >>= 1) sum += __shfl_xor(sum, s);
    out[(size_t)node * 64 + lane] = (v - mm) - logf(sum);
}

extern "C" void kernel_launch(void* const* d_in, const int* in_sizes, int n_in,
                              void* d_out, int out_size, void* d_ws, size_t ws_size,
                              hipStream_t stream) {
    constexpr int IN = 512, HID = 128, OUT = 64;
    const float* feats = (const float*)d_in[0];
    const int*   adj   = (const int*)d_in[1];
    const float* W1 = (const float*)d_in[2];
    const float* b1 = (const float*)d_in[3];
    const float* W2 = (const float*)d_in[4];
    const float* b2 = (const float*)d_in[5];
    const float* W3 = (const float*)d_in[6];
    const float* b3 = (const float*)d_in[7];
    float* out = (float*)d_out;

    const int n = in_sizes[0] / IN;      // 50000
    const int e = in_sizes[1] / 2;       // 800000
    const int* srcp = adj;
    const int* dstp = adj + e;

    // workspace layout
    char* ws = (char*)d_ws;
    int*   deg  = (int*)ws;                    ws += (size_t)n * 4;
    float* dis  = (float*)ws;                  ws += (size_t)n * 4;
    int*   incl = (int*)ws;                    ws += (size_t)n * 4;
    int*   bsum = (int*)ws;                    ws += 256 * 4;
    int*   rs   = (int*)ws;                    ws += (size_t)(n + 1) * 4 + 4;
    int*   curs = (int*)ws;                    ws += (size_t)n * 4;
    unsigned short* cs  = (unsigned short*)ws; ws += (size_t)e * 2;
    unsigned short* Wt1 = (unsigned short*)ws; ws += (size_t)IN * HID * 2;
    unsigned short* Wt2 = (unsigned short*)ws; ws += (size_t)HID * HID * 2;
    unsigned short* Wt3 = (unsigned short*)ws; ws += (size_t)HID * OUT * 2;
    unsigned short* hb  = (unsigned short*)ws; ws += (size_t)n * HID * 2;
    unsigned short* xb  = (unsigned short*)ws; ws += (size_t)n * HID * 2;

    const int nb_n = (n + 255) / 256;
    const int nb_e = (e + 255) / 256;
    const int nb_g = (n + 63) / 64;          // GEMM blocks (64 rows/block)
    const int nb_w = (n * 64 + 255) / 256;   // 1 wave/node kernels
    const int nb_wt = (IN * HID + HID * HID + HID * OUT + 255) / 256;

    // ---- build CSR (by dst) + symmetric norm
    k_zero_i32<<<nb_n, 256, 0, stream>>>(deg, n);
    k_deg_count<<<nb_e, 256, 0, stream>>>(dstp, deg, e);
    k_dis<<<nb_n, 256, 0, stream>>>(deg, dis, n);
    k_scan_block<<<nb_n, 256, 0, stream>>>(deg, incl, bsum, n);
    k_scan_bsum<<<1, 256, 0, stream>>>(bsum, nb_n);
    k_scan_final<<<nb_n, 256, 0, stream>>>(deg, incl, bsum, rs, curs, n, e);
    k_csr_fill16<<<nb_e, 256, 0, stream>>>(srcp, dstp, curs, cs, e);

    // ---- weight transposes (fp32 -> bf16, [K][F] -> [F][K]), one dispatch
    k_wt_all<<<nb_wt, 256, 0, stream>>>(W1, W2, W3, Wt1, Wt2, Wt3);

    // ---- layer 1: 512 -> 128
    k_gemm_bl<IN, HID, false><<<nb_g, 256, 0, stream>>>(feats, Wt1, dis, hb, n);
    k_gather128<true><<<nb_w, 256, 0, stream>>>(rs, cs, dis, hb, b1, xb, n);

    // ---- layer 2: 128 -> 128
    k_gemm_bl<HID, HID, true><<<nb_g, 256, 0, stream>>>(xb, Wt2, dis, hb, n);
    k_gather128<true><<<nb_w, 256, 0, stream>>>(rs, cs, dis, hb, b2, xb, n);

    // ---- layer 3: 128 -> 64
    k_gemm_bl<HID, OUT, true><<<nb_g, 256, 0, stream>>>(xb, Wt3, dis, hb, n);
    k_gather64_lsm<<<nb_w, 256, 0, stream>>>(rs, cs, dis, hb, b3, out, n);
}